// Round 4
// baseline (667.544 us; speedup 1.0000x reference)
//
#include <hip/hip_runtime.h>
#include <hip/hip_bf16.h>

#define IN_CH 256
#define HID 16

typedef __attribute__((ext_vector_type(8))) short bf16x8;
typedef __attribute__((ext_vector_type(4))) float floatx4;

static __device__ __forceinline__ short f2bf(float f) {
    __hip_bfloat16 h = __float2bfloat16(f);   // round-to-nearest-even
    return *reinterpret_cast<short*>(&h);
}

// ---------------- degree count (in-degree of targets) ----------------
__global__ void k_deg(const int* __restrict__ tgt, int* __restrict__ deg, int E) {
    int e = blockIdx.x * blockDim.x + threadIdx.x;
    if (e < E) atomicAdd(&deg[tgt[e]], 1);
}

// ---------------- deg^{-1/2} ----------------
__global__ void k_dis(const int* __restrict__ deg, float* __restrict__ dis, int N) {
    int n = blockIdx.x * blockDim.x + threadIdx.x;
    if (n < N) {
        int d = deg[n];
        dis[n] = (d > 0) ? rsqrtf((float)d) : 0.0f;
    }
}

// ---------------- scan step 1: per-block sums of deg ----------------
__global__ void k_scan1(const int* __restrict__ deg, int* __restrict__ bsum, int N) {
    __shared__ int s[256];
    int i = blockIdx.x * 256 + threadIdx.x;
    s[threadIdx.x] = (i < N) ? deg[i] : 0;
    __syncthreads();
    for (int off = 128; off > 0; off >>= 1) {
        if (threadIdx.x < off) s[threadIdx.x] += s[threadIdx.x + off];
        __syncthreads();
    }
    if (threadIdx.x == 0) bsum[blockIdx.x] = s[0];
}

// ---------------- scan step 2: exclusive scan of block sums (1 block, 512 thr) ----------------
__global__ void k_scan2(int* __restrict__ bsum, int nb) {
    __shared__ int s[512];
    int t = threadIdx.x;
    s[t] = (t < nb) ? bsum[t] : 0;
    __syncthreads();
    for (int off = 1; off < 512; off <<= 1) {
        int add = (t >= off) ? s[t - off] : 0;
        __syncthreads();
        s[t] += add;
        __syncthreads();
    }
    int ex = (t == 0) ? 0 : s[t - 1];
    if (t < nb) bsum[t] = ex;
}

// ---------------- scan step 3: block exclusive scan + offset -> rowptr, cursor ----------------
__global__ void k_scan3(const int* __restrict__ deg, const int* __restrict__ bpre,
                        int* __restrict__ rowptr, int* __restrict__ cursor, int N) {
    __shared__ int s[256];
    int i = blockIdx.x * 256 + threadIdx.x;
    int v = (i < N) ? deg[i] : 0;
    s[threadIdx.x] = v;
    __syncthreads();
    for (int off = 1; off < 256; off <<= 1) {
        int add = (threadIdx.x >= off) ? s[threadIdx.x - off] : 0;
        __syncthreads();
        s[threadIdx.x] += add;
        __syncthreads();
    }
    int excl = s[threadIdx.x] - v + bpre[blockIdx.x];
    if (i < N) { rowptr[i] = excl; cursor[i] = excl; }
}

// ---------------- CSR fill: bucket source ids by target ----------------
__global__ void k_fill(const int* __restrict__ src, const int* __restrict__ tgt,
                       int* __restrict__ cursor, int* __restrict__ csr_src, int E) {
    int e = blockIdx.x * blockDim.x + threadIdx.x;
    if (e < E) {
        int t = tgt[e];
        int pos = atomicAdd(&cursor[t], 1);
        csr_src[pos] = src[e];
    }
}

// ---------------- layer-1 GEMM: h1[n][c] = dis[n] * (x[n]@W1[:,c] + b1[c]) ----------------
__global__ void k_gemm1(const float* __restrict__ x,
                        const float* __restrict__ W1,
                        const float* __restrict__ b1,
                        const float* __restrict__ dis,
                        float* __restrict__ h1, int N) {
    int lane = threadIdx.x & 63;
    int wave = threadIdx.x >> 6;
    int tile = blockIdx.x * 4 + wave;
    int nb = tile * 16;
    if (nb >= N) return;

    int mc = lane & 15;
    int q  = lane >> 4;

    bf16x8 bfrag[8];
#pragma unroll
    for (int kb = 0; kb < 8; kb++) {
#pragma unroll
        for (int j = 0; j < 8; j++) {
            bfrag[kb][j] = f2bf(W1[(kb * 32 + q * 8 + j) * HID + mc]);
        }
    }

    const float* xrow = x + (size_t)(nb + mc) * IN_CH;
    floatx4 acc = {0.f, 0.f, 0.f, 0.f};
#pragma unroll
    for (int kb = 0; kb < 8; kb++) {
        const floatx4* p = (const floatx4*)(xrow + kb * 32 + q * 8);
        floatx4 v0 = p[0];
        floatx4 v1 = p[1];
        bf16x8 afrag;
#pragma unroll
        for (int j = 0; j < 4; j++) {
            afrag[j]     = f2bf(v0[j]);
            afrag[j + 4] = f2bf(v1[j]);
        }
        acc = __builtin_amdgcn_mfma_f32_16x16x32_bf16(afrag, bfrag[kb], acc, 0, 0, 0);
    }

    float bias = b1[mc];
#pragma unroll
    for (int r = 0; r < 4; r++) {
        int node = nb + q * 4 + r;
        if (node < N) {
            h1[(size_t)node * HID + mc] = (acc[r] + bias) * dis[node];
        }
    }
}

// ---------------- gather-aggregate: agg[n][c] = sum_{e: tgt=n} h[src(e)][c] ----------------
// 16 threads per node (one per channel); no atomics, single coalesced write.
__global__ void k_agg(const float* __restrict__ h, const int* __restrict__ csr_src,
                      const int* __restrict__ rowptr, const int* __restrict__ deg,
                      float* __restrict__ aggout, int N) {
    int t = threadIdx.x;
    int n = blockIdx.x * 16 + (t >> 4);
    int c = t & 15;
    if (n >= N) return;
    int start = rowptr[n];
    int cnt = deg[n];
    float acc = 0.f;
    int i = start, end4 = start + (cnt & ~3);
    for (; i < end4; i += 4) {
        int s0 = csr_src[i], s1 = csr_src[i + 1], s2 = csr_src[i + 2], s3 = csr_src[i + 3];
        float v0 = h[16 * (size_t)s0 + c], v1 = h[16 * (size_t)s1 + c];
        float v2 = h[16 * (size_t)s2 + c], v3 = h[16 * (size_t)s3 + c];
        acc += v0 + v1 + v2 + v3;
    }
    for (; i < start + cnt; i++) acc += h[16 * (size_t)csr_src[i] + c];
    aggout[16 * (size_t)n + c] = acc;
}

// ---------------- same, fused final epilogue: out = sigmoid(dis[n] * agg) ----------------
__global__ void k_agg_out(const float* __restrict__ h, const int* __restrict__ csr_src,
                          const int* __restrict__ rowptr, const int* __restrict__ deg,
                          const float* __restrict__ dis, float* __restrict__ out, int N) {
    int t = threadIdx.x;
    int n = blockIdx.x * 16 + (t >> 4);
    int c = t & 15;
    if (n >= N) return;
    int start = rowptr[n];
    int cnt = deg[n];
    float acc = 0.f;
    int i = start, end4 = start + (cnt & ~3);
    for (; i < end4; i += 4) {
        int s0 = csr_src[i], s1 = csr_src[i + 1], s2 = csr_src[i + 2], s3 = csr_src[i + 3];
        float v0 = h[16 * (size_t)s0 + c], v1 = h[16 * (size_t)s1 + c];
        float v2 = h[16 * (size_t)s2 + c], v3 = h[16 * (size_t)s3 + c];
        acc += v0 + v1 + v2 + v3;
    }
    for (; i < start + cnt; i++) acc += h[16 * (size_t)csr_src[i] + c];
    float v = dis[n] * acc;
    out[16 * (size_t)n + c] = 1.0f / (1.0f + __expf(-v));
}

// ---------------- h2 = dis * (sigmoid(dis*agg1) @ W2 + b2) ----------------
__global__ void k_mid(const float* __restrict__ agg1,
                      const float* __restrict__ W2,
                      const float* __restrict__ b2,
                      const float* __restrict__ dis,
                      float* __restrict__ h2, int N) {
    __shared__ float w2s[HID * HID];
    __shared__ float b2s[HID];
    int t = threadIdx.x;
    if (t < HID * HID) w2s[t] = W2[t];
    if (t < HID)       b2s[t] = b2[t];
    __syncthreads();

    int n = blockIdx.x * blockDim.x + t;
    if (n >= N) return;
    float d = dis[n];

    float hs[HID];
#pragma unroll
    for (int c = 0; c < HID; c++) {
        float v = d * agg1[(size_t)n * HID + c];
        hs[c] = 1.0f / (1.0f + __expf(-v));
    }
    float acc[HID];
#pragma unroll
    for (int c2 = 0; c2 < HID; c2++) acc[c2] = b2s[c2];
#pragma unroll
    for (int c = 0; c < HID; c++) {
#pragma unroll
        for (int c2 = 0; c2 < HID; c2++) {
            acc[c2] += hs[c] * w2s[c * HID + c2];
        }
    }
#pragma unroll
    for (int c2 = 0; c2 < HID; c2++) {
        h2[(size_t)n * HID + c2] = acc[c2] * d;
    }
}

extern "C" void kernel_launch(void* const* d_in, const int* in_sizes, int n_in,
                              void* d_out, int out_size, void* d_ws, size_t ws_size,
                              hipStream_t stream) {
    const float* x  = (const float*)d_in[0];
    const int*   ei = (const int*)d_in[1];
    const float* W1 = (const float*)d_in[2];
    const float* b1 = (const float*)d_in[3];
    const float* W2 = (const float*)d_in[4];
    const float* b2 = (const float*)d_in[5];
    float* out = (float*)d_out;

    int N = in_sizes[0] / IN_CH;   // 100000
    int E = in_sizes[1] / 2;       // 3200000
    const int* src = ei;
    const int* tgt = ei + E;

    const int B = 256;
    int NB = (N + B - 1) / B;      // scan blocks (391)

    // workspace: deg | dis | bsum | rowptr | cursor | csr_src | h1(=h2) | agg1
    char* ws = (char*)d_ws;
    auto align256 = [](size_t v) { return (v + 255) & ~(size_t)255; };
    size_t off = 0;
    int*   deg     = (int*)(ws + off);   off += align256((size_t)N * sizeof(int));
    float* dis     = (float*)(ws + off); off += align256((size_t)N * sizeof(float));
    int*   bsum    = (int*)(ws + off);   off += align256((size_t)(NB + 1) * sizeof(int));
    int*   rowptr  = (int*)(ws + off);   off += align256((size_t)N * sizeof(int));
    int*   cursor  = (int*)(ws + off);   off += align256((size_t)N * sizeof(int));
    int*   csr_src = (int*)(ws + off);   off += align256((size_t)E * sizeof(int));
    float* h1      = (float*)(ws + off); off += align256((size_t)N * HID * sizeof(float));
    float* agg1    = (float*)(ws + off); off += align256((size_t)N * HID * sizeof(float));
    float* h2      = h1;  // h1 dead after k_agg; reuse for h2

    hipMemsetAsync(deg, 0, (size_t)N * sizeof(int), stream);

    int grid_deg = (E + B - 1) / B;
    int grid_g1  = ((N + 15) / 16 + 3) / 4;
    int grid_ag  = (N + 15) / 16;

    k_deg  <<<grid_deg, B, 0, stream>>>(tgt, deg, E);
    k_dis  <<<NB, B, 0, stream>>>(deg, dis, N);
    k_scan1<<<NB, B, 0, stream>>>(deg, bsum, N);
    k_scan2<<<1, 512, 0, stream>>>(bsum, NB);
    k_scan3<<<NB, B, 0, stream>>>(deg, bsum, rowptr, cursor, N);
    k_fill <<<grid_deg, B, 0, stream>>>(src, tgt, cursor, csr_src, E);
    k_gemm1<<<grid_g1, B, 0, stream>>>(x, W1, b1, dis, h1, N);
    k_agg  <<<grid_ag, B, 0, stream>>>(h1, csr_src, rowptr, deg, agg1, N);
    k_mid  <<<NB, B, 0, stream>>>(agg1, W2, b2, dis, h2, N);
    k_agg_out<<<grid_ag, B, 0, stream>>>(h2, csr_src, rowptr, deg, dis, out, N);
}